// Round 10
// baseline (49.150 us; speedup 1.0000x reference)
//
#include <hip/hip_runtime.h>
#include <cmath>

// Noisy 8-qubit density-matrix sim, batch 32, depth 6 — single-launch lightcone adjoint.
// E_b = Tr(Λ†(Z0)·rho_b); CPTP adjoints are unital => only 21 stages are nontrivial;
// qubit 7 never enters. ONE 1024-thread block:
//   [15 stages on 6-qubit slab (32KB)] -> [expand ⊗I_q6] -> [T†(5,0)] ->
//   [5 stages block-diag in q6 (128KB slab)] -> [in-LDS contraction with all 32
//   product states, register accumulators, slab-reuse reduction] -> out[32].
// Stage internals (pair-split astage_half, astage_full, split tables, swizzle)
// verbatim from round-9 (passed, absmax 0). Contraction math = round-9 contract
// kernel relocated (Re(O) only: rho is real-symmetric, Im(O) cancels by Hermiticity).

typedef float2 cplx;
#define BATCH 32

__device__ __forceinline__ cplx cmul(cplx a, cplx b){
  return make_float2(a.x*b.x - a.y*b.y, a.x*b.y + a.y*b.x);
}
__device__ __forceinline__ cplx lc(float a, cplx u, float b, cplx v){
  return make_float2(a*u.x + b*v.x, a*u.y + b*v.y);
}
__device__ __forceinline__ cplx sc(float a, cplx u){ return make_float2(a*u.x, a*u.y); }

struct N1C { float A,B,C,D,E; };
__device__ __forceinline__ N1C noise_coeffs(float g){
  float ga = g*0.3f, gp = g*0.2f, p = g*0.5f;
  N1C n;
  n.A = 1.0f - 2.0f*p/3.0f;
  n.D = 2.0f*p/3.0f;
  n.B = ga*n.A + n.D*(1.0f-ga);
  n.E = n.D*ga + n.A*(1.0f-ga);
  n.C = (1.0f - 4.0f*p/3.0f) * sqrtf(1.0f-ga) * sqrtf(1.0f-gp);
  return n;
}
__device__ __forceinline__ N1C mkadj(N1C n){
  N1C a; a.A=n.A; a.B=n.D; a.C=n.C; a.D=n.B; a.E=n.E; return a;
}

__device__ __forceinline__ int physof(int L){
  int rl = L >> 6;
  int rot = ((rl<<3)|(rl>>3)) & 63;
  return L ^ rot;
}
__device__ __forceinline__ constexpr int KPc(int p){
  return (p < 6) ? (1<<p) : ((1<<p) | (1 << (((p-6)+3)%6)));
}

template<int U>
__device__ __forceinline__ int base_for(int g){
  constexpr int P[6][8] = {
    {0,0,0,0,0,0,0,0},
    {9,10,2,4,5, 3,8,11},   // u=1
    {0,10,11,3,5, 4,6,9},   // u=2
    {0,1,11,6,4, 5,7,10},   // u=3
    {1,2,6,7,5, 0,8,11},    // u=4
    {0,2,3,7,8, 1,6,9}};    // u=5
  int b = 0;
  #pragma unroll
  for (int i=0;i<8;i++) b ^= (-((g>>i)&1)) & KPc(P[U][i]);
  return b;
}

__device__ __forceinline__ int base_s(int t){
  constexpr int P[10] = {1,2,3,9, 4,5,7,8,10,11};
  int b = 0;
  #pragma unroll
  for (int i=0;i<10;i++) b ^= (-((t>>i)&1)) & KPc(P[i]);
  return b;
}

__device__ __forceinline__ void rot_pair(cplx& v0, cplx& v1, float cy, float sy){
  cplx a=v0, b=v1;
  v0 = make_float2(cy*a.x - sy*b.x, cy*a.y - sy*b.y);
  v1 = make_float2(sy*a.x + cy*b.x, sy*a.y + cy*b.y);
}

// ---------------- adjoint half-stage (pair-split on row-tgt bit b) ----------------
template<int U>
__device__ __forceinline__ void astage_half(cplx* __restrict__ slab, float4 rc,
                                            int bp, int bsel, N1C n1a, N1C n2a,
                                            float al, float be, float ga, float de){
  constexpr int KA=KPc(6+U), KB=KPc(5+U), KC=1<<U, KD=1<<(U-1);
  int bb = bsel ? KB : 0;
  int xn = bsel ? 0 : (KB^KD);
  cplx h[8], X[4];
  #pragma unroll
  for (int i=0;i<8;i++){
    int a=(i>>2)&1, cc=(i>>1)&1, d=i&1;
    h[i] = slab[bp ^ bb ^ (a?KA:0) ^ (cc?KC:0) ^ (d?KD:0)];
  }
  #pragma unroll
  for (int j=0;j<4;j++){
    int a=j>>1, cc=j&1;
    X[j] = slab[bp ^ xn ^ (a?KA:0) ^ (cc?KC:0)];
  }
  cplx p  = make_float2(rc.z, -rc.w);
  cplx pc = make_float2(rc.z,  rc.w);
  float cy=rc.x, sy=-rc.y;
  #pragma unroll
  for (int d=0;d<2;d++){
    cplx t00=h[d], t11=h[6+d];
    h[d]   = lc(n1a.A,t00, n1a.B,t11);
    h[6+d] = lc(n1a.D,t00, n1a.E,t11);
    h[2+d] = cmul(p,  h[2+d]);
    h[4+d] = cmul(pc, h[4+d]);
  }
  #pragma unroll
  for (int a=0;a<2;a++)
    #pragma unroll
    for (int d=0;d<2;d++) rot_pair(h[a*4+d], h[a*4+2+d], cy, sy);
  #pragma unroll
  for (int cc=0;cc<2;cc++)
    #pragma unroll
    for (int d=0;d<2;d++) rot_pair(h[cc*2+d], h[4+cc*2+d], cy, sy);
  {
    cplx t00=X[0], t11=X[3];
    X[0]=lc(n1a.A,t00, n1a.B,t11);
    X[3]=lc(n1a.D,t00, n1a.E,t11);
    X[1]=cmul(p,X[1]); X[2]=cmul(pc,X[2]);
    rot_pair(X[0],X[1],cy,sy); rot_pair(X[2],X[3],cy,sy);
    rot_pair(X[0],X[2],cy,sy); rot_pair(X[1],X[3],cy,sy);
  }
  #pragma unroll
  for (int j=0;j<4;j++){
    h[2*j]   = lc(al, h[2*j],   be, X[j]);
    h[2*j+1] = lc(ga, h[2*j+1], de, X[j]);
  }
  #pragma unroll
  for (int d=0;d<2;d++){
    cplx t00=h[d], t11=h[6+d];
    h[d]   = lc(n2a.A,t00, n2a.B,t11);
    h[6+d] = lc(n2a.D,t00, n2a.E,t11);
    h[2+d] = sc(n2a.C, h[2+d]);
    h[4+d] = sc(n2a.C, h[4+d]);
  }
  #pragma unroll
  for (int i=0;i<8;i++){
    int a=(i>>2)&1, cc=(i>>1)&1, d=i&1;
    slab[bp ^ (a?KA:0) ^ ((bsel^a)?KB:0) ^ (cc?KC:0) ^ ((d^cc)?KD:0)] = h[i];
  }
}

// ---------------- full-16 adjoint stage, general masks ----------------
template<int KA,int KB,int KC,int KD>
__device__ __forceinline__ void astage_full(cplx* __restrict__ slab, float4 rc,
                                            int bp, N1C n1a, N1C n2a){
  cplx h[16];
  #pragma unroll
  for (int idx=0; idx<16; idx++){
    int a=(idx>>3)&1, b=(idx>>2)&1, cc=(idx>>1)&1, d=idx&1;
    h[idx] = slab[bp ^ (a?KA:0) ^ (b?KB:0) ^ (cc?KC:0) ^ (d?KD:0)];
  }
  {
    cplx p=make_float2(rc.z,-rc.w), pc=make_float2(rc.z,rc.w);
    #pragma unroll
    for (int b=0;b<2;b++)
      #pragma unroll
      for (int d=0;d<2;d++){
        int i=(b<<2)|d;
        cplx t00=h[i], t11=h[i|10];
        h[i]    = lc(n1a.A,t00, n1a.B,t11);
        h[i|10] = lc(n1a.D,t00, n1a.E,t11);
        h[i|2]  = cmul(p,  h[i|2]);
        h[i|8]  = cmul(pc, h[i|8]);
      }
    float cy=rc.x, sy=-rc.y;
    #pragma unroll
    for (int a=0;a<2;a++)
      #pragma unroll
      for (int b=0;b<2;b++)
        #pragma unroll
        for (int d=0;d<2;d++){
          int i=(a<<3)|(b<<2)|d;
          rot_pair(h[i], h[i|2], cy, sy);
        }
    #pragma unroll
    for (int b=0;b<2;b++)
      #pragma unroll
      for (int cc=0;cc<2;cc++)
        #pragma unroll
        for (int d=0;d<2;d++){
          int i=(b<<2)|(cc<<1)|d;
          rot_pair(h[i], h[i|8], cy, sy);
        }
  }
  #pragma unroll
  for (int a=0;a<2;a++)
    #pragma unroll
    for (int cc=0;cc<2;cc++){
      int i=(a<<3)|(cc<<1);
      cplx t00=h[i], t11=h[i|5];
      h[i]   = lc(n2a.A,t00, n2a.B,t11);
      h[i|5] = lc(n2a.D,t00, n2a.E,t11);
      h[i|1] = sc(n2a.C, h[i|1]);
      h[i|4] = sc(n2a.C, h[i|4]);
    }
  #pragma unroll
  for (int b=0;b<2;b++)
    #pragma unroll
    for (int d=0;d<2;d++){
      int i=(b<<2)|d;
      cplx t00=h[i], t11=h[i|10];
      h[i]    = lc(n2a.A,t00, n2a.B,t11);
      h[i|10] = lc(n2a.D,t00, n2a.E,t11);
      h[i|2]  = sc(n2a.C, h[i|2]);
      h[i|8]  = sc(n2a.C, h[i|8]);
    }
  #pragma unroll
  for (int idx=0; idx<16; idx++){
    int a=(idx>>3)&1, b=(idx>>2)&1, cc=(idx>>1)&1, d=idx&1;
    slab[bp ^ (a?KA:0) ^ ((b^a)?KB:0) ^ (cc?KC:0) ^ ((d^cc)?KD:0)] = h[idx];
  }
}

#define ASTGa(l,q,u) { if (t < 512) astage_half<u>(slab, sS[(l)*8+(q)], b##u, bsel, n1a, n2a, al,be,ga,de); __syncthreads(); }
#define ASTGb(q,u)   { astage_half<u>(slab + (subA<<12), sS[(q)], b##u, bsel, n1a, n2a, al,be,ga,de); \
                       astage_half<u>(slab + (subB<<12), sS[(q)], b##u, bsel, n1a, n2a, al,be,ga,de); __syncthreads(); }

// ---------------- everything in one block ----------------
__global__ __launch_bounds__(1024) void fused_kernel(const float* __restrict__ x,
                                                     const float* __restrict__ w,
                                                     float* __restrict__ out){
  __shared__ cplx slab[16384];      // 128 KB
  __shared__ float4 sS[48];
  __shared__ float smAll[896];      // 32 samples x 28 (qubits 0..6 encode 2x2s)
  int t = threadIdx.x;
  int bsel = t & 1;
  int gg = (t >> 1) & 255;
  int subA = (t >> 9) & 1, subB = subA | 2;
  N1C n1a = mkadj(noise_coeffs(0.0003f));
  N1C n2a = mkadj(noise_coeffs(0.0065f));
  float al = bsel ? n2a.C : n2a.A;
  float be = bsel ? 0.f   : n2a.B;
  float ga = bsel ? n2a.E : n2a.C;
  float de = bsel ? n2a.D : 0.f;
  int b1=base_for<1>(gg), b2=base_for<2>(gg), b3=base_for<3>(gg),
      b4=base_for<4>(gg), b5=base_for<5>(gg);
  (void)b1;(void)b2;(void)b3;(void)b4;(void)b5;

  if (t < 48){
    N1C n1 = noise_coeffs(0.0003f);
    float w0=w[t*2], w1=w[t*2+1];
    sS[t] = make_float4(cosf(0.5f*w0), sinf(0.5f*w0), n1.C*cosf(w1), -n1.C*sinf(w1));
  }
  if (t < 256){
    int s = t>>3, q = t&7;
    if (q < 7){
      N1C n1 = noise_coeffs(0.0003f);
      float xv = x[s*8+q];
      float c = cosf(0.5f*xv), sn = sinf(0.5f*xv);
      float p00=c*c, p01=c*sn, p11=sn*sn;
      float* mm = &smAll[s*28 + q*4];
      mm[0]=n1.A*p00+n1.B*p11; mm[1]=n1.C*p01; mm[2]=n1.C*p01; mm[3]=n1.D*p00+n1.E*p11;
    }
  }
  // init O = Z0 ⊗ I on 6-qubit slab (qubit0 = row bit 5)
  #pragma unroll
  for (int i=0;i<4;i++){
    int L = i*1024 + t, rl = L>>6, cl = L&63;
    slab[physof(L)] = make_float2((rl==cl) ? ((rl&32)? -1.f : 1.f) : 0.f, 0.f);
  }
  __syncthreads();

  // layers 5..1: 15 nontrivial stages on the 4096-el slab (U = 5-q)
  ASTGa(5,0,5)
  ASTGa(4,1,4) ASTGa(4,0,5)
  ASTGa(3,2,3) ASTGa(3,1,4) ASTGa(3,0,5)
  ASTGa(2,3,2) ASTGa(2,2,3) ASTGa(2,1,4) ASTGa(2,0,5)
  ASTGa(1,4,1) ASTGa(1,3,2) ASTGa(1,2,3) ASTGa(1,1,4) ASTGa(1,0,5)

  // expand to 7 qubits: O ⊗ I_q6
  #pragma unroll
  for (int i=0;i<4;i++){
    int e = i*1024 + t;
    cplx v = slab[e];
    slab[(3<<12)|e] = v;
    slab[(1<<12)|e] = make_float2(0.f,0.f);
    slab[(2<<12)|e] = make_float2(0.f,0.f);
  }
  __syncthreads();

  // T†(5,0): qubit5 (ctl) x qubit6 (tgt, bits 13/12)
  astage_full<KPc(6), (1<<13), 1, (1<<12)>(slab, sS[5], base_s(t), n1a, n2a);
  __syncthreads();

  // T†(4..0,0): block-diagonal in qubit 6
  ASTGb(4,1) ASTGb(3,2) ASTGb(2,3) ASTGb(1,4) ASTGb(0,5)

  // ---- load this thread's 16 Re(O) elements, then slab is dead ----
  float Oi[16];
  #pragma unroll
  for (int i=0;i<16;i++){
    int el = i*1024 + t;
    Oi[i] = slab[(el & (3<<12)) | physof(el & 4095)].x;
  }
  __syncthreads();   // all reads done before slab reuse

  // ---- contraction: el bits -> cl = t&63 (qubits 0..5 cols, bit 5-q);
  //      rows q2..q5 = t>>6 (4 bits); rows q0,q1 = i bits 1,0; sub = i>>2 = (r6<<1)|c6
  float* fslab = (float*)slab;
  int cl = t & 63, rh = t >> 6;
  int c0=(cl>>5)&1, c1=(cl>>4)&1, c2=(cl>>3)&1, c3=(cl>>2)&1, c4=(cl>>1)&1, c5=cl&1;
  int r2=(rh>>3)&1, r3=(rh>>2)&1, r4=(rh>>1)&1, r5=rh&1;
  #pragma unroll
  for (int chunk=0; chunk<2; chunk++){
    float acc[16];
    #pragma unroll
    for (int sl=0; sl<16; sl++){
      const float* ms = &smAll[(chunk*16+sl)*28];
      float wbase = ms[8  + r2*2 + c2] * ms[12 + r3*2 + c3]
                  * ms[16 + r4*2 + c4] * ms[20 + r5*2 + c5];
      float u[4] = { ms[0+c0]*ms[4+c1],  ms[0+c0]*ms[6+c1],
                     ms[2+c0]*ms[4+c1],  ms[2+c0]*ms[6+c1] };   // u[(r0<<1)|r1]
      float m6v[4] = { ms[24], ms[25], ms[26], ms[27] };        // [r6*2+c6]
      float a = 0.f;
      #pragma unroll
      for (int i=0;i<16;i++) a += Oi[i] * u[i&3] * m6v[i>>2];
      acc[sl] = a * wbase;
    }
    // reduce through freed slab: arr[s][t]
    #pragma unroll
    for (int sl=0; sl<16; sl++) fslab[sl*1024 + t] = acc[sl];
    __syncthreads();
    {
      int wv = t >> 6, ln = t & 63;     // wave wv reduces sample chunk*16+wv
      float v = 0.f;
      #pragma unroll
      for (int k=0;k<16;k++) v += fslab[wv*1024 + ln + 64*k];
      #pragma unroll
      for (int off=32; off>0; off>>=1) v += __shfl_down(v, off, 64);
      if (ln == 0) out[chunk*16 + wv] = v;
    }
    __syncthreads();
  }
}

extern "C" void kernel_launch(void* const* d_in, const int* in_sizes, int n_in,
                              void* d_out, int out_size, void* d_ws, size_t ws_size,
                              hipStream_t stream) {
  const float* x = (const float*)d_in[0];   // [32,8]
  const float* w = (const float*)d_in[1];   // [6,8,2]
  float* out = (float*)d_out;               // [32,1] f32

  fused_kernel<<<1, 1024, 0, stream>>>(x, w, out);
}

// Round 11
// 42.626 us; speedup vs baseline: 1.1531x; 1.1531x over previous
//
#include <hip/hip_runtime.h>
#include <cmath>

// Noisy 8-qubit density-matrix sim, batch 32, depth 6 — lightcone adjoint, 4-way split.
// E_b = Tr(Λ†(Z0)·rho_b); CPTP adjoints unital => 21 nontrivial stages; qubit 7 never
// enters. Kernel 1 (1 block, 1024 thr): backward-evolve O in LDS. Kernel 2 (32 blocks):
// contract with product states (round-9 verbatim).
// NEW: each 16-el stage group split 4 ways on (b,d) (row/col target bits) across lanes
// t^{1,2}; the N2t† cross-coupling ((0,0)<->(1,1)) is a __shfl_xor(...,3) (same-wave,
// DPP quad-perm) with per-thread (alpha,beta): (A,B),(C,0),(C,0),(E,D). All 1024
// threads active on early stages; late block-diag stages do 4 sub-slabs/thread (ILP).

typedef float2 cplx;
#define BATCH 32

__device__ __forceinline__ cplx cmul(cplx a, cplx b){
  return make_float2(a.x*b.x - a.y*b.y, a.x*b.y + a.y*b.x);
}
__device__ __forceinline__ cplx lc(float a, cplx u, float b, cplx v){
  return make_float2(a*u.x + b*v.x, a*u.y + b*v.y);
}
__device__ __forceinline__ cplx sc(float a, cplx u){ return make_float2(a*u.x, a*u.y); }

struct N1C { float A,B,C,D,E; };
__device__ __forceinline__ N1C noise_coeffs(float g){
  float ga = g*0.3f, gp = g*0.2f, p = g*0.5f;
  N1C n;
  n.A = 1.0f - 2.0f*p/3.0f;
  n.D = 2.0f*p/3.0f;
  n.B = ga*n.A + n.D*(1.0f-ga);
  n.E = n.D*ga + n.A*(1.0f-ga);
  n.C = (1.0f - 4.0f*p/3.0f) * sqrtf(1.0f-ga) * sqrtf(1.0f-gp);
  return n;
}
__device__ __forceinline__ N1C mkadj(N1C n){
  N1C a; a.A=n.A; a.B=n.D; a.C=n.C; a.D=n.B; a.E=n.E; return a;
}

__device__ __forceinline__ int physof(int L){
  int rl = L >> 6;
  int rot = ((rl<<3)|(rl>>3)) & 63;
  return L ^ rot;
}
__device__ __forceinline__ constexpr int KPc(int p){
  return (p < 6) ? (1<<p) : ((1<<p) | (1 << (((p-6)+3)%6)));
}

// 4-way split: lane = (g<<2)|(bsel<<1)|dsel. g bits -> free logical positions.
// Bank-pair coverage (c(p)=p<6?p:(p-3)%6): {c(U-1), c(5+U), c(P[0]), c(P[1])} distinct per U.
template<int U>
__device__ __forceinline__ int base4(int g){
  constexpr int P[6][8] = {
    {0,0,0,0,0,0,0,0},
    {10,2, 3,4,5,8,9,11},   // U=1 (active {0,1,6,7})
    {0,11, 3,4,5,6,9,10},   // U=2 (active {1,2,7,8})
    {0,1,  4,5,6,7,10,11},  // U=3 (active {2,3,8,9})
    {1,2,  0,5,6,7,8,11},   // U=4 (active {3,4,9,10})
    {0,2,  1,3,6,7,8,9}};   // U=5 (active {4,5,10,11})
  int b = 0;
  #pragma unroll
  for (int i=0;i<8;i++) b ^= (-((g>>i)&1)) & KPc(P[U][i]);
  return b;
}

// free bits for T†(5,0) full-16 stage (10 bits over positions <=11 + raw bits 12,13)
__device__ __forceinline__ int base_s(int t){
  constexpr int P[10] = {1,2,3,9, 4,5,7,8,10,11};
  int b = 0;
  #pragma unroll
  for (int i=0;i<10;i++) b ^= (-((t>>i)&1)) & KPc(P[i]);
  return b;
}

__device__ __forceinline__ void rot_pair(cplx& v0, cplx& v1, float cy, float sy){
  cplx a=v0, b=v1;
  v0 = make_float2(cy*a.x - sy*b.x, cy*a.y - sy*b.y);
  v1 = make_float2(sy*a.x + cy*b.x, sy*a.y + cy*b.y);
}

// ---------------- 4-way adjoint stage: thread owns fixed (b,d)=(bsel,dsel), 4 els ----------------
// v[j], j=(a<<1)|cc. Sequence: gather -> Rctl†(sparse,rots) -> N2t†(shfl cross) -> N2c† -> scatter+fold
template<int U>
__device__ __forceinline__ void astage_q4(cplx* __restrict__ slab, float4 rc, int bp,
                                          int bsel, int dsel, N1C n1a, N1C n2a,
                                          float alpha, float beta){
  constexpr int KA=KPc(6+U), KB=KPc(5+U), KC=1<<U, KD=1<<(U-1);
  int fix = (bsel?KB:0) ^ (dsel?KD:0);
  cplx v[4];
  v[0] = slab[bp ^ fix];
  v[1] = slab[bp ^ fix ^ KC];
  v[2] = slab[bp ^ fix ^ KA];
  v[3] = slab[bp ^ fix ^ KA ^ KC];
  // Rctl† on (a,cc): sparse adjoint (N1†·Drz†) then Y(-θ) rotations
  cplx p  = make_float2(rc.z, -rc.w);
  cplx pc = make_float2(rc.z,  rc.w);
  float cy=rc.x, sy=-rc.y;
  {
    cplx t00=v[0], t11=v[3];
    v[0]=lc(n1a.A,t00, n1a.B,t11);
    v[3]=lc(n1a.D,t00, n1a.E,t11);
    v[1]=cmul(p,v[1]); v[2]=cmul(pc,v[2]);
    rot_pair(v[0],v[1],cy,sy); rot_pair(v[2],v[3],cy,sy);   // cc rot
    rot_pair(v[0],v[2],cy,sy); rot_pair(v[1],v[3],cy,sy);   // a rot
  }
  // N2t† cross on (b,d): partner at lane^3 ((0,0)<->(1,1); (0,1)<->(1,0) recv unused, beta=0)
  #pragma unroll
  for (int j=0;j<4;j++){
    float rx = __shfl_xor(v[j].x, 3, 64);
    float ry = __shfl_xor(v[j].y, 3, 64);
    v[j] = make_float2(alpha*v[j].x + beta*rx, alpha*v[j].y + beta*ry);
  }
  // N2c† on (a,cc)
  {
    cplx t00=v[0], t11=v[3];
    v[0]=lc(n2a.A,t00, n2a.B,t11);
    v[3]=lc(n2a.D,t00, n2a.E,t11);
    v[1]=sc(n2a.C,v[1]); v[2]=sc(n2a.C,v[2]);
  }
  // scatter with CNOT fold (row b'=bsel^a, col d'=dsel^cc)
  int sb = bsel ? KB : 0;
  slab[bp ^ sb            ^ (dsel?KD:0)]      = v[0];              // a=0,cc=0
  slab[bp ^ sb ^ KC       ^ (dsel?0:KD)]      = v[1];              // a=0,cc=1 (d'=dsel^1)
  slab[bp ^ (sb^KB) ^ KA  ^ (dsel?KD:0)]      = v[2];              // a=1,cc=0 (b'=bsel^1)
  slab[bp ^ (sb^KB) ^ KA ^ KC ^ (dsel?0:KD)]  = v[3];              // a=1,cc=1
}

// ---------------- full-16 adjoint stage, general masks (round-9 verbatim) ----------------
template<int KA,int KB,int KC,int KD>
__device__ __forceinline__ void astage_full(cplx* __restrict__ slab, float4 rc,
                                            int bp, N1C n1a, N1C n2a){
  cplx h[16];
  #pragma unroll
  for (int idx=0; idx<16; idx++){
    int a=(idx>>3)&1, b=(idx>>2)&1, cc=(idx>>1)&1, d=idx&1;
    h[idx] = slab[bp ^ (a?KA:0) ^ (b?KB:0) ^ (cc?KC:0) ^ (d?KD:0)];
  }
  {
    cplx p=make_float2(rc.z,-rc.w), pc=make_float2(rc.z,rc.w);
    #pragma unroll
    for (int b=0;b<2;b++)
      #pragma unroll
      for (int d=0;d<2;d++){
        int i=(b<<2)|d;
        cplx t00=h[i], t11=h[i|10];
        h[i]    = lc(n1a.A,t00, n1a.B,t11);
        h[i|10] = lc(n1a.D,t00, n1a.E,t11);
        h[i|2]  = cmul(p,  h[i|2]);
        h[i|8]  = cmul(pc, h[i|8]);
      }
    float cy=rc.x, sy=-rc.y;
    #pragma unroll
    for (int a=0;a<2;a++)
      #pragma unroll
      for (int b=0;b<2;b++)
        #pragma unroll
        for (int d=0;d<2;d++){
          int i=(a<<3)|(b<<2)|d;
          rot_pair(h[i], h[i|2], cy, sy);
        }
    #pragma unroll
    for (int b=0;b<2;b++)
      #pragma unroll
      for (int cc=0;cc<2;cc++)
        #pragma unroll
        for (int d=0;d<2;d++){
          int i=(b<<2)|(cc<<1)|d;
          rot_pair(h[i], h[i|8], cy, sy);
        }
  }
  #pragma unroll
  for (int a=0;a<2;a++)
    #pragma unroll
    for (int cc=0;cc<2;cc++){
      int i=(a<<3)|(cc<<1);
      cplx t00=h[i], t11=h[i|5];
      h[i]   = lc(n2a.A,t00, n2a.B,t11);
      h[i|5] = lc(n2a.D,t00, n2a.E,t11);
      h[i|1] = sc(n2a.C, h[i|1]);
      h[i|4] = sc(n2a.C, h[i|4]);
    }
  #pragma unroll
  for (int b=0;b<2;b++)
    #pragma unroll
    for (int d=0;d<2;d++){
      int i=(b<<2)|d;
      cplx t00=h[i], t11=h[i|10];
      h[i]    = lc(n2a.A,t00, n2a.B,t11);
      h[i|10] = lc(n2a.D,t00, n2a.E,t11);
      h[i|2]  = sc(n2a.C, h[i|2]);
      h[i|8]  = sc(n2a.C, h[i|8]);
    }
  #pragma unroll
  for (int idx=0; idx<16; idx++){
    int a=(idx>>3)&1, b=(idx>>2)&1, cc=(idx>>1)&1, d=idx&1;
    slab[bp ^ (a?KA:0) ^ ((b^a)?KB:0) ^ (cc?KC:0) ^ ((d^cc)?KD:0)] = h[idx];
  }
}

#define ASTGa(l,q,u) { astage_q4<u>(slab, sS[(l)*8+(q)], b##u, bsel, dsel, n1a, n2a, alpha, beta); __syncthreads(); }
#define ASTGb(q,u)   { _Pragma("unroll") \
                       for (int sub=0; sub<4; sub++) \
                         astage_q4<u>(slab + (sub<<12), sS[(q)], b##u, bsel, dsel, n1a, n2a, alpha, beta); \
                       __syncthreads(); }

// ---------------- backward pass: one block, 1024 threads ----------------
__global__ __launch_bounds__(1024,4) void backward_kernel(const float* __restrict__ w,
                                                          float* __restrict__ Og){
  __shared__ cplx slab[16384];      // 128 KB: 4 sub-blocks (r6,c6) x 4096
  __shared__ float4 sS[48];
  int t = threadIdx.x;
  int dsel = t & 1, bsel = (t >> 1) & 1;
  int gg = t >> 2;                  // 256 groups
  N1C n1a = mkadj(noise_coeffs(0.0003f));
  N1C n2a = mkadj(noise_coeffs(0.0065f));
  float alpha = (bsel==dsel) ? (bsel ? n2a.E : n2a.A) : n2a.C;
  float beta  = (bsel==dsel) ? (bsel ? n2a.D : n2a.B) : 0.f;
  int b1=base4<1>(gg), b2=base4<2>(gg), b3=base4<3>(gg),
      b4=base4<4>(gg), b5=base4<5>(gg);
  (void)b1;(void)b2;(void)b3;(void)b4;(void)b5;

  if (t < 48){
    N1C n1 = noise_coeffs(0.0003f);
    float w0=w[t*2], w1=w[t*2+1];
    sS[t] = make_float4(cosf(0.5f*w0), sinf(0.5f*w0), n1.C*cosf(w1), -n1.C*sinf(w1));
  }
  // init O = Z0 ⊗ I on 6-qubit slab (qubit0 = row bit 5)
  #pragma unroll
  for (int i=0;i<4;i++){
    int L = i*1024 + t, rl = L>>6, cl = L&63;
    slab[physof(L)] = make_float2((rl==cl) ? ((rl&32)? -1.f : 1.f) : 0.f, 0.f);
  }
  __syncthreads();

  // layers 5..1: 15 nontrivial stages on the 4096-el slab (U = 5-q), all 1024 threads
  ASTGa(5,0,5)
  ASTGa(4,1,4) ASTGa(4,0,5)
  ASTGa(3,2,3) ASTGa(3,1,4) ASTGa(3,0,5)
  ASTGa(2,3,2) ASTGa(2,2,3) ASTGa(2,1,4) ASTGa(2,0,5)
  ASTGa(1,4,1) ASTGa(1,3,2) ASTGa(1,2,3) ASTGa(1,1,4) ASTGa(1,0,5)

  // expand to 7 qubits: O ⊗ I_q6
  #pragma unroll
  for (int i=0;i<4;i++){
    int e = i*1024 + t;
    cplx v = slab[e];
    slab[(3<<12)|e] = v;
    slab[(1<<12)|e] = make_float2(0.f,0.f);
    slab[(2<<12)|e] = make_float2(0.f,0.f);
  }
  __syncthreads();

  // T†(5,0): qubit5 (ctl) x qubit6 (tgt, bits 13/12)
  astage_full<KPc(6), (1<<13), 1, (1<<12)>(slab, sS[5], base_s(t), n1a, n2a);
  __syncthreads();

  // T†(4..0,0): block-diagonal in qubit 6 -> 4 sub-slabs per thread (independent, ILP)
  ASTGb(4,1) ASTGb(3,2) ASTGb(2,3) ASTGb(1,4) ASTGb(0,5)

  // write Re(O): Og[sub*4096 + L12]
  #pragma unroll
  for (int i=0;i<16;i++){
    int el = i*1024 + t;
    Og[el] = slab[(el & (3<<12)) | physof(el & 4095)].x;
  }
}

// ---------------- contraction (round-9 verbatim): E_b = sum O[r,c] * prod_q m_q[r_q,c_q] ----------------
__global__ __launch_bounds__(256) void contract_kernel(const float* __restrict__ Og,
                                                       const float* __restrict__ x,
                                                       float* __restrict__ out){
  __shared__ float sm[28];   // qubits 0..6 encode 2x2s
  __shared__ float red[4];
  int t = threadIdx.x, s = blockIdx.x;
  if (t < 7){
    N1C n1 = noise_coeffs(0.0003f);
    float xv = x[s*8+t];
    float c = cosf(0.5f*xv), sn = sinf(0.5f*xv);
    float p00=c*c, p01=c*sn, p11=sn*sn;
    sm[t*4+0]=n1.A*p00+n1.B*p11; sm[t*4+1]=n1.C*p01;
    sm[t*4+2]=n1.C*p01;          sm[t*4+3]=n1.D*p00+n1.E*p11;
  }
  __syncthreads();
  int cl = t & 63;           // col bits (qubit q <-> bit 5-q)
  int r45 = t >> 6;          // row bits of qubits 4,5
  float w0;
  {
    int c4=(cl>>1)&1, c5=cl&1;
    w0 = sm[16 + ((r45>>1)&1)*2 + c4] * sm[20 + (r45&1)*2 + c5];
  }
  int c0=(cl>>5)&1, c1=(cl>>4)&1, c2=(cl>>3)&1, c3=(cl>>2)&1;
  float g0[2]={sm[0+c0],  sm[2+c0]};
  float g1[2]={sm[4+c1],  sm[6+c1]};
  float g2[2]={sm[8+c2],  sm[10+c2]};
  float g3[2]={sm[12+c3], sm[14+c3]};
  float m6v[4]={sm[24], sm[25], sm[26], sm[27]};
  float acc = 0.f;
  #pragma unroll
  for (int i=0;i<64;i++){
    int el = i*256 + t;     // sub=i>>4; rl bits5..2 = i bits3..0; rl bits1..0 = r45
    float wq = w0 * g0[(i>>3)&1] * g1[(i>>2)&1] * g2[(i>>1)&1] * g3[i&1] * m6v[i>>4];
    acc += Og[el] * wq;
  }
  #pragma unroll
  for (int off=32; off>0; off>>=1) acc += __shfl_down(acc, off, 64);
  if ((t&63)==0) red[t>>6] = acc;
  __syncthreads();
  if (t==0) out[s] = red[0]+red[1]+red[2]+red[3];
}

extern "C" void kernel_launch(void* const* d_in, const int* in_sizes, int n_in,
                              void* d_out, int out_size, void* d_ws, size_t ws_size,
                              hipStream_t stream) {
  const float* x = (const float*)d_in[0];   // [32,8]
  const float* w = (const float*)d_in[1];   // [6,8,2]
  float* out = (float*)d_out;               // [32,1] f32
  float* Og  = (float*)d_ws;                // 64 KB: Re(O), 7-qubit operator

  backward_kernel<<<1, 1024, 0, stream>>>(w, Og);
  contract_kernel<<<BATCH, 256, 0, stream>>>(Og, x, out);
}